// Round 10
// baseline (201.394 us; speedup 1.0000x reference)
//
#include <hip/hip_runtime.h>
#include <stdint.h>

typedef __bf16 bf16x8 __attribute__((ext_vector_type(8)));
typedef float f32x4 __attribute__((ext_vector_type(4)));

// ---------- bf16 helpers ----------
__device__ inline float bf2f(uint16_t u) {
    uint32_t x = ((uint32_t)u) << 16;
    float f;
    __builtin_memcpy(&f, &x, 4);
    return f;
}
__device__ inline uint16_t f2bf(float f) {
    uint32_t x;
    __builtin_memcpy(&x, &f, 4);
    uint32_t r = (x + 0x7FFFu + ((x >> 16) & 1u)) >> 16;
    return (uint16_t)r;
}

// ---------------------------------------------------------------------------
// Merged small weight prep (one launch).
// ---------------------------------------------------------------------------
__global__ __launch_bounds__(256) void k_prep_small(const float* __restrict__ W2,
                                                    const float* __restrict__ W1,
                                                    const float* __restrict__ Wa,
                                                    uint16_t* __restrict__ wA,
                                                    uint16_t* __restrict__ wA1c,
                                                    uint16_t* __restrict__ waP) {
    int bid = blockIdx.x;
    int tid = threadIdx.x;
    if (bid < 72) {
        int j = bid * 256 + tid;
        if (j >= 18432) return;
        int t = j >> 11, rem = j & 2047, oc = rem >> 5, ic = rem & 31;
        int dy = t / 3, dx = t - dy * 3;
        wA[j] = f2bf(W2[(oc * 32 + ic) * 9 + dy * 3 + dx]);
    } else if (bid < 84) {
        int j = (bid - 72) * 256 + tid;
        if (j >= 3072) return;
        int dy = j >> 10, rem = j & 1023, oc = rem >> 5, k = rem & 31;
        int dx = k >> 2, ic = k & 3;
        uint16_t v = 0;
        if (dx < 3 && ic < 3) v = f2bf(W1[((oc * 3 + ic) * 3 + dy) * 3 + dx]);
        wA1c[j] = v;
    } else {
        int j = (bid - 84) * 256 + tid;
        if (j >= 4096) return;
        int chunk = j >> 10, ks = (j >> 9) & 1, tl = (j >> 5) & 15, ch = j & 31;
        int t = chunk * 16 + tl;
        int cg = ks * 32 + ch;
        waP[j] = (t < 49) ? f2bf(Wa[cg * 49 + t]) : (uint16_t)0;
    }
}

// Wfc f32 -> bf16, PERMUTED k-order to match NHWC pooled2: k_new = px*64+ch
__global__ __launch_bounds__(256) void k_prep_wfc(const float* __restrict__ Wfc,
                                                  uint16_t* __restrict__ wfcb) {
    int o = blockIdx.x;        // 0..49
    int pb = blockIdx.y;       // 0..15
    int ch = threadIdx.x & 63;
    int pr = threadIdx.x >> 6; // 0..3
    const float* src = Wfc + (size_t)o * 65536 + ch * 1024;
    uint16_t* dst = wfcb + (size_t)o * 65536 + ch;
#pragma unroll 4
    for (int i = 0; i < 16; ++i) {
        int px = pb * 64 + i * 4 + pr;
        dst[(size_t)px * 64] = f2bf(src[px]);
    }
}

// ---------------------------------------------------------------------------
// Kernel A: handcrafted features. One block per (channel, image).
// ---------------------------------------------------------------------------
__global__ __launch_bounds__(256) void k_handcrafted(const float* __restrict__ img,
                                                     float* __restrict__ f) {
    __shared__ float p[128 * 129];  // 66048 B
    int c = blockIdx.x, b = blockIdx.y;
    const float* src = img + (((size_t)(b * 3 + c)) << 14);
    int tid = threadIdx.x;
    float sum = 0.f, sumsq = 0.f;
    for (int it = 0; it < 64; ++it) {
        int idx = tid + (it << 8);
        int r = idx >> 7, cc = idx & 127;
        float v = floorf(src[idx] * 255.0f);
        p[r * 129 + cc] = v;
        sum += v;
        sumsq += v * v;
    }
    __syncthreads();
    {
        int r = tid >> 1;
        int c0 = (tid & 1) * 64;
        int rm = (r == 0) ? 1 : (r - 1), rp = (r == 127) ? 126 : (r + 1);
        const float* Pm = &p[rm * 129];
        const float* P0 = &p[r * 129];
        const float* Pp = &p[rp * 129];
        float am, a0, ap, bm, b0, bp, cm, c0v, cp;
        if (c0 == 0) {
            a0 = Pm[0]; ap = Pm[1]; am = ap;
            b0 = P0[0]; bp = P0[1]; bm = bp;
            c0v = Pp[0]; cp = Pp[1]; cm = cp;
        } else {
            am = Pm[63]; a0 = Pm[64]; ap = Pm[65];
            bm = P0[63]; b0 = P0[64]; bp = P0[65];
            cm = Pp[63]; c0v = Pp[64]; cp = Pp[65];
        }
        float esum = 0.f;
        for (int i = 0; i < 64; ++i) {
            float gx = (ap - am) + 2.f * (bp - bm) + (cp - cm);
            float gy = (cm + 2.f * c0v + cp) - (am + 2.f * a0 + ap);
            esum += sqrtf(gx * gx + gy * gy);
            if (i < 63) {
                int nc = c0 + i + 2;
                am = a0; a0 = ap;
                bm = b0; b0 = bp;
                cm = c0v; c0v = cp;
                if (nc <= 127) {
                    ap = Pm[nc];
                    bp = P0[nc];
                    cp = Pp[nc];
                } else {
                    ap = am;
                    bp = bm;
                    cp = cm;
                }
            }
        }
        for (int off = 32; off; off >>= 1) {
            sum += __shfl_down(sum, off);
            sumsq += __shfl_down(sumsq, off);
            esum += __shfl_down(esum, off);
        }
        __syncthreads();
        int w = tid >> 6;
        if ((tid & 63) == 0) {
            p[w * 3 + 0] = sum;
            p[w * 3 + 1] = sumsq;
            p[w * 3 + 2] = esum;
        }
        __syncthreads();
        if (tid == 0) {
            float S = 0.f, Q = 0.f, E = 0.f;
            for (int i = 0; i < 4; ++i) {
                S += p[i * 3 + 0];
                Q += p[i * 3 + 1];
                E += p[i * 3 + 2];
            }
            const float inv = 1.0f / 16384.0f;
            float mean = S * inv;
            float var = Q * inv - mean * mean;
            f[b * 16 + c] = E * inv;
            f[b * 16 + 3 + c] = mean;
            f[b * 16 + 6 + c] = sqrtf(fmaxf(var, 0.f));
        }
    }
}

// ---------------------------------------------------------------------------
// Kernel B: conv1 via MFMA, direct NHWC-padded fragment reads.
// ---------------------------------------------------------------------------
__global__ __launch_bounds__(256) void k_conv1_mfma(const float* __restrict__ img,
                                                    const uint16_t* __restrict__ wA1c,
                                                    const float* __restrict__ b1,
                                                    uint16_t* __restrict__ pooled1) {
    __shared__ uint16_t s_nhwc[18 * 34 * 4 + 32];  // 4960 B
    __shared__ uint16_t s_out[8 * 16 * 32];        // 8192 B
    const int tile = blockIdx.x;
    const int b = blockIdx.y;
    const int ty = tile >> 2, tx = tile & 3;
    const int Y0 = ty * 16, X0 = tx * 32;
    const int tid = threadIdx.x;

    for (int j = tid; j < 612; j += 256) {
        int r = j / 34, sc = j - r * 34;
        int gy = Y0 - 1 + r, gx = X0 - 1 + sc;
        uint16_t d[4] = {0, 0, 0, 0};
        if ((unsigned)gy < 128u && (unsigned)gx < 128u) {
            size_t base = (((size_t)b * 3) << 14) + (gy << 7) + gx;
#pragma unroll
            for (int ic = 0; ic < 3; ++ic) d[ic] = f2bf(img[base + ((size_t)ic << 14)]);
        }
        *(uint2*)&s_nhwc[j * 4] = *(uint2*)d;
    }

    const int wv = tid >> 6, lane = tid & 63;
    const int rowl = lane & 15, kg = lane >> 4;

    bf16x8 afr[3][2];
#pragma unroll
    for (int dy = 0; dy < 3; ++dy)
#pragma unroll
        for (int g = 0; g < 2; ++g)
            afr[dy][g] = *(const bf16x8*)(wA1c + dy * 1024 + (g * 16 + rowl) * 32 + kg * 8);
    float bias[2][4];
#pragma unroll
    for (int g = 0; g < 2; ++g)
#pragma unroll
        for (int r = 0; r < 4; ++r)
            bias[g][r] = b1[g * 16 + kg * 4 + r];

    __syncthreads();

#pragma unroll
    for (int pr = 0; pr < 2; ++pr) {
#pragma unroll
        for (int seg = 0; seg < 2; ++seg) {
            const int y0 = wv * 4 + pr * 2;
            const int xl = seg * 16 + rowl;
            bf16x8 bw[4];
#pragma unroll
            for (int rr = 0; rr < 4; ++rr) {
                const uint16_t* rp = &s_nhwc[((y0 + rr) * 34 + xl + kg * 2) * 4];
                uint2 lo = *(const uint2*)rp;
                uint2 hi = *(const uint2*)(rp + 4);
                union { uint2 u[2]; bf16x8 v; } u;
                u.u[0] = lo;
                u.u[1] = hi;
                bw[rr] = u.v;
            }
            f32x4 acc0[2], acc1[2];
#pragma unroll
            for (int g = 0; g < 2; ++g)
#pragma unroll
                for (int r = 0; r < 4; ++r) {
                    acc0[g][r] = bias[g][r];
                    acc1[g][r] = bias[g][r];
                }
#pragma unroll
            for (int dy = 0; dy < 3; ++dy)
#pragma unroll
                for (int g = 0; g < 2; ++g) {
                    acc0[g] = __builtin_amdgcn_mfma_f32_16x16x32_bf16(afr[dy][g], bw[dy], acc0[g], 0, 0, 0);
                    acc1[g] = __builtin_amdgcn_mfma_f32_16x16x32_bf16(afr[dy][g], bw[dy + 1], acc1[g], 0, 0, 0);
                }
#pragma unroll
            for (int g = 0; g < 2; ++g)
#pragma unroll
                for (int r = 0; r < 4; ++r) {
                    float m = fmaxf(acc0[g][r], acc1[g][r]);
                    m = fmaxf(m, 0.f);
                    float o = fmaxf(m, __shfl_xor(m, 1));
                    if (!(lane & 1)) {
                        int prow = wv * 2 + pr;
                        int pcol = seg * 8 + (rowl >> 1);
                        int oc = g * 16 + kg * 4 + r;
                        s_out[(prow * 16 + pcol) * 32 + oc] = f2bf(o);
                    }
                }
        }
    }
    __syncthreads();
    for (int u = tid; u < 512; u += 256) {
        int px = u >> 2, c = u & 3;
        int prow = px >> 4, pcol = px & 15;
        uint4 v = *(const uint4*)&s_out[px * 32 + c * 8];
        ((uint4*)pooled1)[((((size_t)b << 12) + (ty * 8 + prow) * 64 + tx * 16 + pcol) << 2) + c] = v;
    }
}

// ---------------------------------------------------------------------------
// Kernel C: conv2 via MFMA. Two y-half passes (acc[4][2] = 32 VGPR) + afr
// pinned in registers via empty-asm redefinition (blocks rematerialization).
// Output NHWC [B][1024 px][64 oc].
// ---------------------------------------------------------------------------
__global__ __launch_bounds__(256) void k_conv2_mfma(const uint16_t* __restrict__ pooled1,
                                                    const uint16_t* __restrict__ wA,
                                                    const float* __restrict__ b2v,
                                                    uint16_t* __restrict__ pooled2n) {
    __shared__ uint16_t s_in[10 * 34 * 32];   // 21760 B
    __shared__ uint16_t s_out[64 * 64];       // 8192 B: [pixel][oc ^ swz]
    const int bx = blockIdx.x;
    const int b = blockIdx.y;
    const int tx = bx >> 3, ty = bx & 7;
    const int X0 = tx * 32, Y0 = ty * 8;
    const int tid = threadIdx.x;

    for (int j = tid; j < 1360; j += 256) {
        int r = j / 136;
        int rem = j - r * 136;
        int px = rem >> 2, c4 = rem & 3;
        int gy = Y0 - 1 + r, gx = X0 - 1 + px;
        uint4 v = make_uint4(0, 0, 0, 0);
        if ((unsigned)gy < 64u && (unsigned)gx < 64u)
            v = ((const uint4*)pooled1)[((((size_t)b << 12) + gy * 64 + gx) << 2) + c4];
        *(uint4*)&s_in[(r * 34 + px) * 32 + c4 * 8] = v;
    }

    const int wv = tid >> 6, lane = tid & 63;
    const int ocq = wv & 1, xth = wv >> 1;
    const int rowl = lane & 15, kg = lane >> 4;

    bf16x8 afr[9][2];
#pragma unroll
    for (int t = 0; t < 9; ++t)
#pragma unroll
        for (int g = 0; g < 2; ++g) {
            afr[t][g] = *(const bf16x8*)(wA + t * 2048 + (ocq * 32 + g * 16 + rowl) * 32 + kg * 8);
            asm volatile("" : "+v"(afr[t][g]));  // pin: forbid rematerialization
        }
    float bias[2][4];
#pragma unroll
    for (int g = 0; g < 2; ++g)
#pragma unroll
        for (int r = 0; r < 4; ++r)
            bias[g][r] = b2v[ocq * 32 + g * 16 + kg * 4 + r];

    __syncthreads();

#pragma unroll
    for (int h = 0; h < 2; ++h) {
        f32x4 acc[4][2];
#pragma unroll
        for (int y = 0; y < 4; ++y)
#pragma unroll
            for (int g = 0; g < 2; ++g)
#pragma unroll
                for (int r = 0; r < 4; ++r) acc[y][g][r] = bias[g][r];

#pragma unroll
        for (int rl = 0; rl < 6; ++rl) {
            const int r = 4 * h + rl;
            bf16x8 R[3];
#pragma unroll
            for (int dx = 0; dx < 3; ++dx) {
                int pix = r * 34 + xth * 16 + rowl + dx;
                R[dx] = *(const bf16x8*)(s_in + pix * 32 + kg * 8);
            }
#pragma unroll
            for (int dyp = 0; dyp < 3; ++dyp) {
                const int y = rl - dyp;
                if (y >= 0 && y < 4) {
#pragma unroll
                    for (int dx = 0; dx < 3; ++dx) {
                        const int t = dyp * 3 + dx;
#pragma unroll
                        for (int g = 0; g < 2; ++g)
                            acc[y][g] = __builtin_amdgcn_mfma_f32_16x16x32_bf16(afr[t][g], R[dx], acc[y][g], 0, 0, 0);
                    }
                }
            }
        }
        // pool 2x2 + relu for this half's 2 pooled rows
#pragma unroll
        for (int i = 0; i < 2; ++i) {
#pragma unroll
            for (int g = 0; g < 2; ++g)
#pragma unroll
                for (int rr = 0; rr < 4; ++rr) {
                    float m = fmaxf(acc[2 * i][g][rr], acc[2 * i + 1][g][rr]);
                    m = fmaxf(m, 0.f);
                    float o = fmaxf(m, __shfl_xor(m, 1));
                    if (!(lane & 1)) {
                        int oc = ocq * 32 + g * 16 + kg * 4 + rr;
                        int pxl = xth * 8 + (rowl >> 1);
                        int pl = (h * 2 + i) * 16 + pxl;
                        s_out[pl * 64 + (oc ^ ((pxl & 7) << 3))] = f2bf(o);
                    }
                }
        }
    }
    __syncthreads();
    const int PY0 = ty * 4, PX0 = tx * 16;
    for (int u = tid; u < 512; u += 256) {
        int pl = u >> 3, c = u & 7;
        int py = pl >> 4, pxl = pl & 15;
        uint4 v = *(const uint4*)&s_out[pl * 64 + ((c ^ (pxl & 7)) << 3)];
        *(uint4*)&pooled2n[((((size_t)b << 10) + (PY0 + py) * 32 + PX0 + pxl) << 6) + c * 8] = v;
    }
}

// ---------------------------------------------------------------------------
// Kernel D1: attention conv via pointwise-GEMM + shift-add.
// ---------------------------------------------------------------------------
__global__ __launch_bounds__(256) void k_attn_gemm(const uint16_t* __restrict__ pooled2n,
                                                   const uint16_t* __restrict__ waP,
                                                   const float* __restrict__ ba,
                                                   float* __restrict__ attn) {
    __shared__ uint16_t P[448 * 70];  // 62720 B
    const int qt = blockIdx.x;
    const int b = blockIdx.y;
    const int tid = threadIdx.x;
    const int R0 = qt * 8;
    const int wv = tid >> 6, lane = tid & 63;
    const int rowl = lane & 15, kg = lane >> 4;

    bf16x8 afr[4][2];
#pragma unroll
    for (int c = 0; c < 4; ++c)
#pragma unroll
        for (int ks = 0; ks < 2; ++ks)
            afr[c][ks] = *(const bf16x8*)(waP + ((c * 2 + ks) * 16 + rowl) * 32 + kg * 8);

    for (int nt = wv; nt < 28; nt += 4) {
        int hpx = nt * 16 + rowl;
        int hrow = hpx >> 5, hcol = hpx & 31;
        int gy = R0 - 3 + hrow;
        bf16x8 bf0, bf1;
        if ((unsigned)gy < 32u) {
            const uint16_t* src = pooled2n + ((((size_t)b << 10) + (gy << 5) + hcol) << 6);
            bf0 = *(const bf16x8*)(src + kg * 8);
            bf1 = *(const bf16x8*)(src + 32 + kg * 8);
        } else {
            union { uint4 u; bf16x8 v; } z;
            z.u = make_uint4(0, 0, 0, 0);
            bf0 = z.v;
            bf1 = z.v;
        }
        f32x4 acc[4];
#pragma unroll
        for (int c = 0; c < 4; ++c)
#pragma unroll
            for (int r = 0; r < 4; ++r) acc[c][r] = 0.f;
#pragma unroll
        for (int c = 0; c < 4; ++c) {
            acc[c] = __builtin_amdgcn_mfma_f32_16x16x32_bf16(afr[c][0], bf0, acc[c], 0, 0, 0);
            acc[c] = __builtin_amdgcn_mfma_f32_16x16x32_bf16(afr[c][1], bf1, acc[c], 0, 0, 0);
        }
#pragma unroll
        for (int c = 0; c < 4; ++c) {
            uint32_t lo = (uint32_t)f2bf(acc[c][0]) | ((uint32_t)f2bf(acc[c][1]) << 16);
            uint32_t hi = (uint32_t)f2bf(acc[c][2]) | ((uint32_t)f2bf(acc[c][3]) << 16);
            uint16_t* dst = &P[hpx * 70 + c * 16 + kg * 4];
            *(uint32_t*)dst = lo;
            *(uint32_t*)(dst + 2) = hi;
        }
    }
    __syncthreads();

    const int pyl = tid >> 5, px = tid & 31;
    float v = ba[0];
#pragma unroll
    for (int dy = 0; dy < 7; ++dy) {
        int hl = pyl + dy;
#pragma unroll
        for (int dx = 0; dx < 7; ++dx) {
            int qx = px + dx - 3;
            if ((unsigned)qx < 32u) v += bf2f(P[(hl * 32 + qx) * 70 + dy * 7 + dx]);
        }
    }
    attn[((size_t)b << 10) + qt * 256 + tid] = 1.f / (1.f + __expf(-v));
}

// ---------------------------------------------------------------------------
// Kernel D2: FC via MFMA, NHWC k-order (k = px*64+ch), wfcb permuted to match.
// ---------------------------------------------------------------------------
__global__ __launch_bounds__(256) void k_fc_mfma(const uint16_t* __restrict__ pooled2n,
                                                 const float* __restrict__ attn,
                                                 const uint16_t* __restrict__ wfcb,
                                                 float* __restrict__ partial) {
    __shared__ uint16_t xh[128 * 128];  // 32 KB
    const int it = blockIdx.x;   // 0..15
    const int kc = blockIdx.y;   // 0..63
    const int b0 = it * 16;
    const int K0 = kc * 1024;
    const int tid = threadIdx.x;

    for (int j = tid; j < 2048; j += 256) {
        int im = j >> 7, k8 = j & 127;
        int bimg = b0 + im;
        int gk = K0 + k8 * 8;
        int px = gk >> 6, ch0 = gk & 63;
        uint4 pv = *(const uint4*)&pooled2n[((((size_t)bimg << 10) + px) << 6) + ch0];
        float a = attn[((size_t)bimg << 10) + px];
        uint16_t s[8];
        *(uint4*)s = pv;
        uint16_t d[8];
#pragma unroll
        for (int i = 0; i < 8; ++i) d[i] = f2bf(bf2f(s[i]) * a);
        *(uint4*)&xh[k8 * 128 + im * 8] = *(uint4*)d;
    }

    const int wv = tid >> 6, lane = tid & 63;
    const int rowl = lane & 15, kg = lane >> 4;
    const uint16_t* wbase = wfcb + (size_t)(wv * 16 + rowl) * 65536 + K0 + kg * 8;

    __syncthreads();

    f32x4 acc = {0.f, 0.f, 0.f, 0.f};
#pragma unroll 4
    for (int kk = 0; kk < 32; ++kk) {
        bf16x8 af = *(const bf16x8*)(wbase + kk * 32);
        bf16x8 bf = *(const bf16x8*)&xh[(kk * 4 + kg) * 128 + rowl * 8];
        acc = __builtin_amdgcn_mfma_f32_16x16x32_bf16(af, bf, acc, 0, 0, 0);
    }
    float* pp = &partial[(((size_t)kc * 256 + (b0 + rowl)) << 6) + wv * 16 + kg * 4];
    *(f32x4*)pp = acc;
}

// ---------------------------------------------------------------------------
// Kernel E: MLP head + fusion. One wave per image.
// ---------------------------------------------------------------------------
__global__ __launch_bounds__(64) void k_head(const float* __restrict__ fbuf,
                                             const float* __restrict__ partial,
                                             const float* __restrict__ Wh1, const float* __restrict__ bh1,
                                             const float* __restrict__ Wh2, const float* __restrict__ bh2,
                                             const float* __restrict__ Wh3, const float* __restrict__ bh3,
                                             const float* __restrict__ bfc,
                                             const float* __restrict__ Wf, const float* __restrict__ bf_,
                                             const float* __restrict__ Wc, const float* __restrict__ bc,
                                             float* __restrict__ out) {
    __shared__ float fl[9];
    __shared__ float h1[32];
    __shared__ float h2[64];
    __shared__ float cat[100];
    int b = blockIdx.x;
    int l = threadIdx.x;
    if (l < 9) fl[l] = fbuf[b * 16 + l];
    __syncthreads();
    if (l < 32) {
        float a = bh1[l];
        for (int i = 0; i < 9; ++i) a += fl[i] * Wh1[l * 9 + i];
        h1[l] = fmaxf(a, 0.f);
    }
    __syncthreads();
    {
        float a = bh2[l];
        for (int i = 0; i < 32; ++i) a += h1[i] * Wh2[l * 32 + i];
        h2[l] = fmaxf(a, 0.f);
    }
    __syncthreads();
    if (l < 50) {
        float a = bh3[l];
        for (int i = 0; i < 64; ++i) a += h2[i] * Wh3[l * 64 + i];
        cat[50 + l] = fmaxf(a, 0.f);
        float s = bfc[l];
        for (int kc2 = 0; kc2 < 64; ++kc2) s += partial[(((size_t)kc2 * 256 + b) << 6) + l];
        cat[l] = fmaxf(s, 0.f);
    }
    __syncthreads();
    float a = bf_[l];
    for (int i = 0; i < 100; ++i) a += cat[i] * Wf[l * 100 + i];
    a = fmaxf(a, 0.f);
    float v = a * Wc[l];
    for (int off = 32; off; off >>= 1) v += __shfl_down(v, off);
    if (l == 0) out[b] = 1.f / (1.f + __expf(-(v + bc[0])));
}

// ---------------------------------------------------------------------------
extern "C" void kernel_launch(void* const* d_in, const int* in_sizes, int n_in,
                              void* d_out, int out_size, void* d_ws, size_t ws_size,
                              hipStream_t stream) {
    const float* images = (const float*)d_in[0];
    const float* W1 = (const float*)d_in[1];
    const float* b1 = (const float*)d_in[2];
    const float* W2 = (const float*)d_in[3];
    const float* b2 = (const float*)d_in[4];
    const float* Wa = (const float*)d_in[5];
    const float* ba = (const float*)d_in[6];
    const float* Wfc = (const float*)d_in[7];
    const float* bfc = (const float*)d_in[8];
    const float* Wh1 = (const float*)d_in[9];
    const float* bh1 = (const float*)d_in[10];
    const float* Wh2 = (const float*)d_in[11];
    const float* bh2 = (const float*)d_in[12];
    const float* Wh3 = (const float*)d_in[13];
    const float* bh3 = (const float*)d_in[14];
    const float* Wf = (const float*)d_in[15];
    const float* bf_ = (const float*)d_in[16];
    const float* Wc = (const float*)d_in[17];
    const float* bc = (const float*)d_in[18];

    const size_t NEEDED = 102828032;
    if (ws_size < NEEDED) return;

    char* ws = (char*)d_ws;
    uint16_t* pooled1 = (uint16_t*)ws;
    uint16_t* pooled2n = (uint16_t*)(ws + 67108864);
    float* attn = (float*)(ws + 100663296);
    float* fbuf = (float*)(ws + 101711872);
    uint16_t* wA = (uint16_t*)(ws + 102776832);
    uint16_t* wA1c = (uint16_t*)(ws + 102813696);
    uint16_t* waP = (uint16_t*)(ws + 102819840);
    uint16_t* wfcb = (uint16_t*)ws;            // alias pooled1 (dead after conv2)
    float* partial = (float*)(ws + 16777216);  // alias pooled1 (dead after conv2)
    float* out = (float*)d_out;

    hipLaunchKernelGGL(k_prep_small, dim3(100), dim3(256), 0, stream, W2, W1, Wa, wA, wA1c, waP);
    hipLaunchKernelGGL(k_handcrafted, dim3(3, 256), dim3(256), 0, stream, images, fbuf);
    hipLaunchKernelGGL(k_conv1_mfma, dim3(32, 256), dim3(256), 0, stream, images, wA1c, b1, pooled1);
    hipLaunchKernelGGL(k_conv2_mfma, dim3(16, 256), dim3(256), 0, stream, pooled1, wA, b2, pooled2n);
    // pooled1 dead from here
    hipLaunchKernelGGL(k_prep_wfc, dim3(50, 16), dim3(256), 0, stream, Wfc, wfcb);
    hipLaunchKernelGGL(k_attn_gemm, dim3(4, 256), dim3(256), 0, stream, pooled2n, waP, ba, attn);
    hipLaunchKernelGGL(k_fc_mfma, dim3(16, 64), dim3(256), 0, stream, pooled2n, attn, wfcb, partial);
    hipLaunchKernelGGL(k_head, dim3(256), dim3(64), 0, stream, fbuf, partial,
                       Wh1, bh1, Wh2, bh2, Wh3, bh3, bfc, Wf, bf_, Wc, bc, out);
}

// Round 11
// 171.049 us; speedup vs baseline: 1.1774x; 1.1774x over previous
//
#include <hip/hip_runtime.h>
#include <stdint.h>

typedef __bf16 bf16x8 __attribute__((ext_vector_type(8)));
typedef float f32x4 __attribute__((ext_vector_type(4)));

// ---------- bf16 helpers ----------
__device__ inline float bf2f(uint16_t u) {
    uint32_t x = ((uint32_t)u) << 16;
    float f;
    __builtin_memcpy(&f, &x, 4);
    return f;
}
__device__ inline uint16_t f2bf(float f) {
    uint32_t x;
    __builtin_memcpy(&x, &f, 4);
    uint32_t r = (x + 0x7FFFu + ((x >> 16) & 1u)) >> 16;
    return (uint16_t)r;
}

// ---------------------------------------------------------------------------
// Merged small weight prep (one launch).
// ---------------------------------------------------------------------------
__global__ __launch_bounds__(256) void k_prep_small(const float* __restrict__ W2,
                                                    const float* __restrict__ W1,
                                                    const float* __restrict__ Wa,
                                                    uint16_t* __restrict__ wA,
                                                    uint16_t* __restrict__ wA1c,
                                                    uint16_t* __restrict__ waP) {
    int bid = blockIdx.x;
    int tid = threadIdx.x;
    if (bid < 72) {
        int j = bid * 256 + tid;
        if (j >= 18432) return;
        int t = j >> 11, rem = j & 2047, oc = rem >> 5, ic = rem & 31;
        int dy = t / 3, dx = t - dy * 3;
        wA[j] = f2bf(W2[(oc * 32 + ic) * 9 + dy * 3 + dx]);
    } else if (bid < 84) {
        int j = (bid - 72) * 256 + tid;
        if (j >= 3072) return;
        int dy = j >> 10, rem = j & 1023, oc = rem >> 5, k = rem & 31;
        int dx = k >> 2, ic = k & 3;
        uint16_t v = 0;
        if (dx < 3 && ic < 3) v = f2bf(W1[((oc * 3 + ic) * 3 + dy) * 3 + dx]);
        wA1c[j] = v;
    } else {
        int j = (bid - 84) * 256 + tid;
        if (j >= 4096) return;
        int chunk = j >> 10, ks = (j >> 9) & 1, tl = (j >> 5) & 15, ch = j & 31;
        int t = chunk * 16 + tl;
        int cg = ks * 32 + ch;
        waP[j] = (t < 49) ? f2bf(Wa[cg * 49 + t]) : (uint16_t)0;
    }
}

// ---------------------------------------------------------------------------
// Wfc f32 -> bf16, permuted k-order (k_new = px*64+ch), via LDS tile-transpose.
// Grid (50, 8): per block one oc row, 128-px tile. Coalesced f32 reads along
// px, coalesced bf16 writes along ch (512 B per wave).
// ---------------------------------------------------------------------------
__global__ __launch_bounds__(256) void k_prep_wfc(const float* __restrict__ Wfc,
                                                  uint16_t* __restrict__ wfcb) {
    __shared__ uint16_t sT[64][132];  // [ch][px_local], padded stride
    int o = blockIdx.x;        // 0..49
    int px0 = blockIdx.y * 128;
    int tid = threadIdx.x;
#pragma unroll
    for (int p = 0; p < 8; ++p) {
        int idx = p * 256 + tid;          // 0..2047: ch x 32 float4 chunks
        int ch = idx >> 5, c4 = idx & 31;
        float4 v = *(const float4*)&Wfc[(size_t)o * 65536 + ch * 1024 + px0 + c4 * 4];
        ushort4 u;
        u.x = f2bf(v.x);
        u.y = f2bf(v.y);
        u.z = f2bf(v.z);
        u.w = f2bf(v.w);
        *(ushort4*)&sT[ch][c4 * 4] = u;
    }
    __syncthreads();
#pragma unroll
    for (int p = 0; p < 8; ++p) {
        int idx = p * 256 + tid;          // 0..2047: 128 px x 16 ch-chunks
        int pxl = idx >> 4, c = idx & 15;
        ushort4 u;
        u.x = sT[4 * c + 0][pxl];
        u.y = sT[4 * c + 1][pxl];
        u.z = sT[4 * c + 2][pxl];
        u.w = sT[4 * c + 3][pxl];
        *(ushort4*)&wfcb[(size_t)o * 65536 + (size_t)(px0 + pxl) * 64 + c * 4] = u;
    }
}

// ---------------------------------------------------------------------------
// Kernel A: handcrafted features. One block per (channel, image).
// ---------------------------------------------------------------------------
__global__ __launch_bounds__(256) void k_handcrafted(const float* __restrict__ img,
                                                     float* __restrict__ f) {
    __shared__ float p[128 * 129];  // 66048 B
    int c = blockIdx.x, b = blockIdx.y;
    const float* src = img + (((size_t)(b * 3 + c)) << 14);
    int tid = threadIdx.x;
    float sum = 0.f, sumsq = 0.f;
    for (int it = 0; it < 64; ++it) {
        int idx = tid + (it << 8);
        int r = idx >> 7, cc = idx & 127;
        float v = floorf(src[idx] * 255.0f);
        p[r * 129 + cc] = v;
        sum += v;
        sumsq += v * v;
    }
    __syncthreads();
    {
        int r = tid >> 1;
        int c0 = (tid & 1) * 64;
        int rm = (r == 0) ? 1 : (r - 1), rp = (r == 127) ? 126 : (r + 1);
        const float* Pm = &p[rm * 129];
        const float* P0 = &p[r * 129];
        const float* Pp = &p[rp * 129];
        float am, a0, ap, bm, b0, bp, cm, c0v, cp;
        if (c0 == 0) {
            a0 = Pm[0]; ap = Pm[1]; am = ap;
            b0 = P0[0]; bp = P0[1]; bm = bp;
            c0v = Pp[0]; cp = Pp[1]; cm = cp;
        } else {
            am = Pm[63]; a0 = Pm[64]; ap = Pm[65];
            bm = P0[63]; b0 = P0[64]; bp = P0[65];
            cm = Pp[63]; c0v = Pp[64]; cp = Pp[65];
        }
        float esum = 0.f;
        for (int i = 0; i < 64; ++i) {
            float gx = (ap - am) + 2.f * (bp - bm) + (cp - cm);
            float gy = (cm + 2.f * c0v + cp) - (am + 2.f * a0 + ap);
            esum += sqrtf(gx * gx + gy * gy);
            if (i < 63) {
                int nc = c0 + i + 2;
                am = a0; a0 = ap;
                bm = b0; b0 = bp;
                cm = c0v; c0v = cp;
                if (nc <= 127) {
                    ap = Pm[nc];
                    bp = P0[nc];
                    cp = Pp[nc];
                } else {
                    ap = am;
                    bp = bm;
                    cp = cm;
                }
            }
        }
        for (int off = 32; off; off >>= 1) {
            sum += __shfl_down(sum, off);
            sumsq += __shfl_down(sumsq, off);
            esum += __shfl_down(esum, off);
        }
        __syncthreads();
        int w = tid >> 6;
        if ((tid & 63) == 0) {
            p[w * 3 + 0] = sum;
            p[w * 3 + 1] = sumsq;
            p[w * 3 + 2] = esum;
        }
        __syncthreads();
        if (tid == 0) {
            float S = 0.f, Q = 0.f, E = 0.f;
            for (int i = 0; i < 4; ++i) {
                S += p[i * 3 + 0];
                Q += p[i * 3 + 1];
                E += p[i * 3 + 2];
            }
            const float inv = 1.0f / 16384.0f;
            float mean = S * inv;
            float var = Q * inv - mean * mean;
            f[b * 16 + c] = E * inv;
            f[b * 16 + 3 + c] = mean;
            f[b * 16 + 6 + c] = sqrtf(fmaxf(var, 0.f));
        }
    }
}

// ---------------------------------------------------------------------------
// Kernel B: conv1 via MFMA, direct NHWC-padded fragment reads.
// ---------------------------------------------------------------------------
__global__ __launch_bounds__(256) void k_conv1_mfma(const float* __restrict__ img,
                                                    const uint16_t* __restrict__ wA1c,
                                                    const float* __restrict__ b1,
                                                    uint16_t* __restrict__ pooled1) {
    __shared__ uint16_t s_nhwc[18 * 34 * 4 + 32];  // 4960 B
    __shared__ uint16_t s_out[8 * 16 * 32];        // 8192 B
    const int tile = blockIdx.x;
    const int b = blockIdx.y;
    const int ty = tile >> 2, tx = tile & 3;
    const int Y0 = ty * 16, X0 = tx * 32;
    const int tid = threadIdx.x;

    for (int j = tid; j < 612; j += 256) {
        int r = j / 34, sc = j - r * 34;
        int gy = Y0 - 1 + r, gx = X0 - 1 + sc;
        uint16_t d[4] = {0, 0, 0, 0};
        if ((unsigned)gy < 128u && (unsigned)gx < 128u) {
            size_t base = (((size_t)b * 3) << 14) + (gy << 7) + gx;
#pragma unroll
            for (int ic = 0; ic < 3; ++ic) d[ic] = f2bf(img[base + ((size_t)ic << 14)]);
        }
        *(uint2*)&s_nhwc[j * 4] = *(uint2*)d;
    }

    const int wv = tid >> 6, lane = tid & 63;
    const int rowl = lane & 15, kg = lane >> 4;

    bf16x8 afr[3][2];
#pragma unroll
    for (int dy = 0; dy < 3; ++dy)
#pragma unroll
        for (int g = 0; g < 2; ++g)
            afr[dy][g] = *(const bf16x8*)(wA1c + dy * 1024 + (g * 16 + rowl) * 32 + kg * 8);
    float bias[2][4];
#pragma unroll
    for (int g = 0; g < 2; ++g)
#pragma unroll
        for (int r = 0; r < 4; ++r)
            bias[g][r] = b1[g * 16 + kg * 4 + r];

    __syncthreads();

#pragma unroll
    for (int pr = 0; pr < 2; ++pr) {
#pragma unroll
        for (int seg = 0; seg < 2; ++seg) {
            const int y0 = wv * 4 + pr * 2;
            const int xl = seg * 16 + rowl;
            bf16x8 bw[4];
#pragma unroll
            for (int rr = 0; rr < 4; ++rr) {
                const uint16_t* rp = &s_nhwc[((y0 + rr) * 34 + xl + kg * 2) * 4];
                uint2 lo = *(const uint2*)rp;
                uint2 hi = *(const uint2*)(rp + 4);
                union { uint2 u[2]; bf16x8 v; } u;
                u.u[0] = lo;
                u.u[1] = hi;
                bw[rr] = u.v;
            }
            f32x4 acc0[2], acc1[2];
#pragma unroll
            for (int g = 0; g < 2; ++g)
#pragma unroll
                for (int r = 0; r < 4; ++r) {
                    acc0[g][r] = bias[g][r];
                    acc1[g][r] = bias[g][r];
                }
#pragma unroll
            for (int dy = 0; dy < 3; ++dy)
#pragma unroll
                for (int g = 0; g < 2; ++g) {
                    acc0[g] = __builtin_amdgcn_mfma_f32_16x16x32_bf16(afr[dy][g], bw[dy], acc0[g], 0, 0, 0);
                    acc1[g] = __builtin_amdgcn_mfma_f32_16x16x32_bf16(afr[dy][g], bw[dy + 1], acc1[g], 0, 0, 0);
                }
#pragma unroll
            for (int g = 0; g < 2; ++g)
#pragma unroll
                for (int r = 0; r < 4; ++r) {
                    float m = fmaxf(acc0[g][r], acc1[g][r]);
                    m = fmaxf(m, 0.f);
                    float o = fmaxf(m, __shfl_xor(m, 1));
                    if (!(lane & 1)) {
                        int prow = wv * 2 + pr;
                        int pcol = seg * 8 + (rowl >> 1);
                        int oc = g * 16 + kg * 4 + r;
                        s_out[(prow * 16 + pcol) * 32 + oc] = f2bf(o);
                    }
                }
        }
    }
    __syncthreads();
    for (int u = tid; u < 512; u += 256) {
        int px = u >> 2, c = u & 3;
        int prow = px >> 4, pcol = px & 15;
        uint4 v = *(const uint4*)&s_out[px * 32 + c * 8];
        ((uint4*)pooled1)[((((size_t)b << 12) + (ty * 8 + prow) * 64 + tx * 16 + pcol) << 2) + c] = v;
    }
}

// ---------------------------------------------------------------------------
// Kernel C: conv2 via MFMA implicit GEMM (round-8 proven version).
// Output NHWC [B][1024 px][64 oc].
// ---------------------------------------------------------------------------
__global__ __launch_bounds__(256) void k_conv2_mfma(const uint16_t* __restrict__ pooled1,
                                                    const uint16_t* __restrict__ wA,
                                                    const float* __restrict__ b2v,
                                                    uint16_t* __restrict__ pooled2n) {
    __shared__ uint16_t s_in[10 * 34 * 32];   // 21760 B
    __shared__ uint16_t s_out[64 * 64];       // 8192 B: [pixel][oc ^ swz]
    const int bx = blockIdx.x;
    const int b = blockIdx.y;
    const int tx = bx >> 3, ty = bx & 7;
    const int X0 = tx * 32, Y0 = ty * 8;
    const int tid = threadIdx.x;

    for (int j = tid; j < 1360; j += 256) {
        int r = j / 136;
        int rem = j - r * 136;
        int px = rem >> 2, c4 = rem & 3;
        int gy = Y0 - 1 + r, gx = X0 - 1 + px;
        uint4 v = make_uint4(0, 0, 0, 0);
        if ((unsigned)gy < 64u && (unsigned)gx < 64u)
            v = ((const uint4*)pooled1)[((((size_t)b << 12) + gy * 64 + gx) << 2) + c4];
        *(uint4*)&s_in[(r * 34 + px) * 32 + c4 * 8] = v;
    }

    const int wv = tid >> 6, lane = tid & 63;
    const int ocq = wv & 1, xth = wv >> 1;
    const int rowl = lane & 15, kg = lane >> 4;

    bf16x8 afr[9][2];
#pragma unroll
    for (int t = 0; t < 9; ++t)
#pragma unroll
        for (int g = 0; g < 2; ++g)
            afr[t][g] = *(const bf16x8*)(wA + t * 2048 + (ocq * 32 + g * 16 + rowl) * 32 + kg * 8);
    float bias[2][4];
#pragma unroll
    for (int g = 0; g < 2; ++g)
#pragma unroll
        for (int r = 0; r < 4; ++r)
            bias[g][r] = b2v[ocq * 32 + g * 16 + kg * 4 + r];

    __syncthreads();

    for (int yp = 0; yp < 4; ++yp) {
        f32x4 acc[2][2];
#pragma unroll
        for (int p = 0; p < 2; ++p)
#pragma unroll
            for (int g = 0; g < 2; ++g)
#pragma unroll
                for (int r = 0; r < 4; ++r) acc[p][g][r] = bias[g][r];

        bf16x8 bfr[4][3];
#pragma unroll
        for (int rr = 0; rr < 4; ++rr)
#pragma unroll
            for (int dx = 0; dx < 3; ++dx) {
                int pix = (2 * yp + rr) * 34 + xth * 16 + rowl + dx;
                bfr[rr][dx] = *(const bf16x8*)(s_in + pix * 32 + kg * 8);
            }
#pragma unroll
        for (int dy = 0; dy < 3; ++dy)
#pragma unroll
            for (int dx = 0; dx < 3; ++dx) {
                int t = dy * 3 + dx;
#pragma unroll
                for (int g = 0; g < 2; ++g) {
                    acc[0][g] = __builtin_amdgcn_mfma_f32_16x16x32_bf16(afr[t][g], bfr[dy][dx], acc[0][g], 0, 0, 0);
                    acc[1][g] = __builtin_amdgcn_mfma_f32_16x16x32_bf16(afr[t][g], bfr[dy + 1][dx], acc[1][g], 0, 0, 0);
                }
            }
#pragma unroll
        for (int g = 0; g < 2; ++g)
#pragma unroll
            for (int r = 0; r < 4; ++r) {
                float m = fmaxf(acc[0][g][r], acc[1][g][r]);
                m = fmaxf(m, 0.f);
                float o = fmaxf(m, __shfl_xor(m, 1));
                if (!(lane & 1)) {
                    int oc = ocq * 32 + g * 16 + kg * 4 + r;
                    int pxl = xth * 8 + (rowl >> 1);
                    int pl = yp * 16 + pxl;
                    s_out[pl * 64 + (oc ^ ((pxl & 7) << 3))] = f2bf(o);
                }
            }
    }
    __syncthreads();
    const int PY0 = ty * 4, PX0 = tx * 16;
    for (int u = tid; u < 512; u += 256) {
        int pl = u >> 3, c = u & 7;
        int py = pl >> 4, pxl = pl & 15;
        uint4 v = *(const uint4*)&s_out[pl * 64 + ((c ^ (pxl & 7)) << 3)];
        *(uint4*)&pooled2n[((((size_t)b << 10) + (PY0 + py) * 32 + PX0 + pxl) << 6) + c * 8] = v;
    }
}

// ---------------------------------------------------------------------------
// Kernel D1: attention conv via pointwise-GEMM + shift-add.
// ---------------------------------------------------------------------------
__global__ __launch_bounds__(256) void k_attn_gemm(const uint16_t* __restrict__ pooled2n,
                                                   const uint16_t* __restrict__ waP,
                                                   const float* __restrict__ ba,
                                                   float* __restrict__ attn) {
    __shared__ uint16_t P[448 * 70];  // 62720 B
    const int qt = blockIdx.x;
    const int b = blockIdx.y;
    const int tid = threadIdx.x;
    const int R0 = qt * 8;
    const int wv = tid >> 6, lane = tid & 63;
    const int rowl = lane & 15, kg = lane >> 4;

    bf16x8 afr[4][2];
#pragma unroll
    for (int c = 0; c < 4; ++c)
#pragma unroll
        for (int ks = 0; ks < 2; ++ks)
            afr[c][ks] = *(const bf16x8*)(waP + ((c * 2 + ks) * 16 + rowl) * 32 + kg * 8);

    for (int nt = wv; nt < 28; nt += 4) {
        int hpx = nt * 16 + rowl;
        int hrow = hpx >> 5, hcol = hpx & 31;
        int gy = R0 - 3 + hrow;
        bf16x8 bf0, bf1;
        if ((unsigned)gy < 32u) {
            const uint16_t* src = pooled2n + ((((size_t)b << 10) + (gy << 5) + hcol) << 6);
            bf0 = *(const bf16x8*)(src + kg * 8);
            bf1 = *(const bf16x8*)(src + 32 + kg * 8);
        } else {
            union { uint4 u; bf16x8 v; } z;
            z.u = make_uint4(0, 0, 0, 0);
            bf0 = z.v;
            bf1 = z.v;
        }
        f32x4 acc[4];
#pragma unroll
        for (int c = 0; c < 4; ++c)
#pragma unroll
            for (int r = 0; r < 4; ++r) acc[c][r] = 0.f;
#pragma unroll
        for (int c = 0; c < 4; ++c) {
            acc[c] = __builtin_amdgcn_mfma_f32_16x16x32_bf16(afr[c][0], bf0, acc[c], 0, 0, 0);
            acc[c] = __builtin_amdgcn_mfma_f32_16x16x32_bf16(afr[c][1], bf1, acc[c], 0, 0, 0);
        }
#pragma unroll
        for (int c = 0; c < 4; ++c) {
            uint32_t lo = (uint32_t)f2bf(acc[c][0]) | ((uint32_t)f2bf(acc[c][1]) << 16);
            uint32_t hi = (uint32_t)f2bf(acc[c][2]) | ((uint32_t)f2bf(acc[c][3]) << 16);
            uint16_t* dst = &P[hpx * 70 + c * 16 + kg * 4];
            *(uint32_t*)dst = lo;
            *(uint32_t*)(dst + 2) = hi;
        }
    }
    __syncthreads();

    const int pyl = tid >> 5, px = tid & 31;
    float v = ba[0];
#pragma unroll
    for (int dy = 0; dy < 7; ++dy) {
        int hl = pyl + dy;
#pragma unroll
        for (int dx = 0; dx < 7; ++dx) {
            int qx = px + dx - 3;
            if ((unsigned)qx < 32u) v += bf2f(P[(hl * 32 + qx) * 70 + dy * 7 + dx]);
        }
    }
    attn[((size_t)b << 10) + qt * 256 + tid] = 1.f / (1.f + __expf(-v));
}

// ---------------------------------------------------------------------------
// Kernel D2: FC via MFMA, NHWC k-order. 1D grid of 1024: wg = it*64 + kc so
// that wg%8 == kc%8 -> all 16 image-tile blocks sharing a kc slice land on
// the same XCD (wfcb slice becomes L2-resident once).
// ---------------------------------------------------------------------------
__global__ __launch_bounds__(256) void k_fc_mfma(const uint16_t* __restrict__ pooled2n,
                                                 const float* __restrict__ attn,
                                                 const uint16_t* __restrict__ wfcb,
                                                 float* __restrict__ partial) {
    __shared__ uint16_t xh[128 * 128];  // 32 KB
    const int wg = blockIdx.x;
    const int it = wg >> 6;      // 0..15
    const int kc = wg & 63;      // 0..63
    const int b0 = it * 16;
    const int K0 = kc * 1024;
    const int tid = threadIdx.x;

    for (int j = tid; j < 2048; j += 256) {
        int im = j >> 7, k8 = j & 127;
        int bimg = b0 + im;
        int gk = K0 + k8 * 8;
        int px = gk >> 6, ch0 = gk & 63;
        uint4 pv = *(const uint4*)&pooled2n[((((size_t)bimg << 10) + px) << 6) + ch0];
        float a = attn[((size_t)bimg << 10) + px];
        uint16_t s[8];
        *(uint4*)s = pv;
        uint16_t d[8];
#pragma unroll
        for (int i = 0; i < 8; ++i) d[i] = f2bf(bf2f(s[i]) * a);
        *(uint4*)&xh[k8 * 128 + im * 8] = *(uint4*)d;
    }

    const int wv = tid >> 6, lane = tid & 63;
    const int rowl = lane & 15, kg = lane >> 4;
    const uint16_t* wbase = wfcb + (size_t)(wv * 16 + rowl) * 65536 + K0 + kg * 8;

    __syncthreads();

    f32x4 acc = {0.f, 0.f, 0.f, 0.f};
#pragma unroll 4
    for (int kk = 0; kk < 32; ++kk) {
        bf16x8 af = *(const bf16x8*)(wbase + kk * 32);
        bf16x8 bf = *(const bf16x8*)&xh[(kk * 4 + kg) * 128 + rowl * 8];
        acc = __builtin_amdgcn_mfma_f32_16x16x32_bf16(af, bf, acc, 0, 0, 0);
    }
    float* pp = &partial[(((size_t)kc * 256 + (b0 + rowl)) << 6) + wv * 16 + kg * 4];
    *(f32x4*)pp = acc;
}

// ---------------------------------------------------------------------------
// Kernel E: MLP head + fusion. One wave per image.
// ---------------------------------------------------------------------------
__global__ __launch_bounds__(64) void k_head(const float* __restrict__ fbuf,
                                             const float* __restrict__ partial,
                                             const float* __restrict__ Wh1, const float* __restrict__ bh1,
                                             const float* __restrict__ Wh2, const float* __restrict__ bh2,
                                             const float* __restrict__ Wh3, const float* __restrict__ bh3,
                                             const float* __restrict__ bfc,
                                             const float* __restrict__ Wf, const float* __restrict__ bf_,
                                             const float* __restrict__ Wc, const float* __restrict__ bc,
                                             float* __restrict__ out) {
    __shared__ float fl[9];
    __shared__ float h1[32];
    __shared__ float h2[64];
    __shared__ float cat[100];
    int b = blockIdx.x;
    int l = threadIdx.x;
    if (l < 9) fl[l] = fbuf[b * 16 + l];
    __syncthreads();
    if (l < 32) {
        float a = bh1[l];
        for (int i = 0; i < 9; ++i) a += fl[i] * Wh1[l * 9 + i];
        h1[l] = fmaxf(a, 0.f);
    }
    __syncthreads();
    {
        float a = bh2[l];
        for (int i = 0; i < 32; ++i) a += h1[i] * Wh2[l * 32 + i];
        h2[l] = fmaxf(a, 0.f);
    }
    __syncthreads();
    if (l < 50) {
        float a = bh3[l];
        for (int i = 0; i < 64; ++i) a += h2[i] * Wh3[l * 64 + i];
        cat[50 + l] = fmaxf(a, 0.f);
        float s = bfc[l];
        for (int kc2 = 0; kc2 < 64; ++kc2) s += partial[(((size_t)kc2 * 256 + b) << 6) + l];
        cat[l] = fmaxf(s, 0.f);
    }
    __syncthreads();
    float a = bf_[l];
    for (int i = 0; i < 100; ++i) a += cat[i] * Wf[l * 100 + i];
    a = fmaxf(a, 0.f);
    float v = a * Wc[l];
    for (int off = 32; off; off >>= 1) v += __shfl_down(v, off);
    if (l == 0) out[b] = 1.f / (1.f + __expf(-(v + bc[0])));
}

// ---------------------------------------------------------------------------
extern "C" void kernel_launch(void* const* d_in, const int* in_sizes, int n_in,
                              void* d_out, int out_size, void* d_ws, size_t ws_size,
                              hipStream_t stream) {
    const float* images = (const float*)d_in[0];
    const float* W1 = (const float*)d_in[1];
    const float* b1 = (const float*)d_in[2];
    const float* W2 = (const float*)d_in[3];
    const float* b2 = (const float*)d_in[4];
    const float* Wa = (const float*)d_in[5];
    const float* ba = (const float*)d_in[6];
    const float* Wfc = (const float*)d_in[7];
    const float* bfc = (const float*)d_in[8];
    const float* Wh1 = (const float*)d_in[9];
    const float* bh1 = (const float*)d_in[10];
    const float* Wh2 = (const float*)d_in[11];
    const float* bh2 = (const float*)d_in[12];
    const float* Wh3 = (const float*)d_in[13];
    const float* bh3 = (const float*)d_in[14];
    const float* Wf = (const float*)d_in[15];
    const float* bf_ = (const float*)d_in[16];
    const float* Wc = (const float*)d_in[17];
    const float* bc = (const float*)d_in[18];

    // workspace layout (bytes)
    //   pooled1 bf16 NHWC [256,64,64,32] : 67108864   @ 0
    //     after conv2, reused as:
    //       wfcb    bf16 [50,65536] perm : 6553600    @ 0
    //       partial f32  [64,256,64]     : 4194304    @ 16777216
    //   pooled2n bf16 NHWC [256,1024,64] : 33554432   @ 67108864
    //   attn    f32  [256,1024]          : 1048576    @ 100663296
    //   fbuf    f32  [256,16]            : 16384      @ 101711872
    //   wA      bf16 [9,64,32]           : 36864      @ 102776832
    //   wA1c    bf16 [3,32,32]           : 6144       @ 102813696
    //   waP     bf16 [4,2,16,32]         : 8192       @ 102819840
    const size_t NEEDED = 102828032;
    if (ws_size < NEEDED) return;

    char* ws = (char*)d_ws;
    uint16_t* pooled1 = (uint16_t*)ws;
    uint16_t* pooled2n = (uint16_t*)(ws + 67108864);
    float* attn = (float*)(ws + 100663296);
    float* fbuf = (float*)(ws + 101711872);
    uint16_t* wA = (uint16_t*)(ws + 102776832);
    uint16_t* wA1c = (uint16_t*)(ws + 102813696);
    uint16_t* waP = (uint16_t*)(ws + 102819840);
    uint16_t* wfcb = (uint16_t*)ws;            // alias pooled1 (dead after conv2)
    float* partial = (float*)(ws + 16777216);  // alias pooled1 (dead after conv2)
    float* out = (float*)d_out;

    hipLaunchKernelGGL(k_prep_small, dim3(100), dim3(256), 0, stream, W2, W1, Wa, wA, wA1c, waP);
    hipLaunchKernelGGL(k_handcrafted, dim3(3, 256), dim3(256), 0, stream, images, fbuf);
    hipLaunchKernelGGL(k_conv1_mfma, dim3(32, 256), dim3(256), 0, stream, images, wA1c, b1, pooled1);
    hipLaunchKernelGGL(k_conv2_mfma, dim3(16, 256), dim3(256), 0, stream, pooled1, wA, b2, pooled2n);
    // pooled1 dead from here
    hipLaunchKernelGGL(k_prep_wfc, dim3(50, 8), dim3(256), 0, stream, Wfc, wfcb);
    hipLaunchKernelGGL(k_attn_gemm, dim3(4, 256), dim3(256), 0, stream, pooled2n, waP, ba, attn);
    hipLaunchKernelGGL(k_fc_mfma, dim3(1024), dim3(256), 0, stream, pooled2n, attn, wfcb, partial);
    hipLaunchKernelGGL(k_head, dim3(256), dim3(64), 0, stream, fbuf, partial,
                       Wh1, bh1, Wh2, bh2, Wh3, bh3, bfc, Wf, bf_, Wc, bc, out);
}